// Round 5
// baseline (108.819 us; speedup 1.0000x reference)
//
#include <hip/hip_runtime.h>
#include <hip/hip_cooperative_groups.h>

namespace cg = cooperative_groups;

#define B_   16
#define C_   128
#define N_   2304      // 48*48
#define ZR   256       // 2*C
#define KS   4         // k-splits for gram
#define KPB  (N_/KS)   // 576
#define KC   64        // k per staged chunk (64 bf16 = 8 granules of 16B)
#define NCH  (KPB/KC)  // 9
#define QT   16384     // 128*128 floats per quadrant tile

typedef __bf16 bf16x8 __attribute__((ext_vector_type(8)));
typedef float  f32x4  __attribute__((ext_vector_type(4)));

__device__ __forceinline__ ushort rne16(float f) {
    unsigned u = __float_as_uint(f);
    return (ushort)((u + 0x7FFFu + ((u >> 16) & 1u)) >> 16);   // RNE bf16
}

// ---------------- kernel 1: norms + normalize + bf16 convert (float4) ----
// grid: B_*36 = 576 blocks, 256 threads. Block = 64 columns of one batch.
// Thread (g = t&15, rc = t>>4): col4 g, rows rc*8..rc*8+7. Raw data held in
// registers across the norm reduction (no LDS round-trip for data).
__global__ __launch_bounds__(256) void nc_k(const float* __restrict__ pred,
                                            const float* __restrict__ targ,
                                            ushort* __restrict__ Z) {
    int blk = blockIdx.x;
    int b  = blk / 36;
    int n0 = (blk % 36) * 64;
    int t  = threadIdx.x;
    int g  = t & 15;
    int rc = t >> 4;

    __shared__ float4 rp[16][16];
    __shared__ float4 rq[4][16];
    __shared__ float4 rn4[16];

    for (int side = 0; side < 2; ++side) {
        const float* src = (side ? targ : pred) + (size_t)b * C_ * N_ + n0 + 4 * g;
        float4 raw[8];
        float4 sq = make_float4(0.f, 0.f, 0.f, 0.f);
#pragma unroll
        for (int i = 0; i < 8; ++i) {
            raw[i] = *(const float4*)(src + (size_t)(rc * 8 + i) * N_);
            sq.x = fmaf(raw[i].x, raw[i].x, sq.x);
            sq.y = fmaf(raw[i].y, raw[i].y, sq.y);
            sq.z = fmaf(raw[i].z, raw[i].z, sq.z);
            sq.w = fmaf(raw[i].w, raw[i].w, sq.w);
        }
        rp[rc][g] = sq;
        __syncthreads();
        if (t < 64) {
            int gg = t & 15, h = t >> 4;
            float4 a0 = rp[h * 4 + 0][gg], a1 = rp[h * 4 + 1][gg];
            float4 a2 = rp[h * 4 + 2][gg], a3 = rp[h * 4 + 3][gg];
            rq[h][gg] = make_float4(a0.x + a1.x + a2.x + a3.x,
                                    a0.y + a1.y + a2.y + a3.y,
                                    a0.z + a1.z + a2.z + a3.z,
                                    a0.w + a1.w + a2.w + a3.w);
        }
        __syncthreads();
        if (t < 16) {
            float4 a0 = rq[0][t], a1 = rq[1][t], a2 = rq[2][t], a3 = rq[3][t];
            float4 s = make_float4(a0.x + a1.x + a2.x + a3.x,
                                   a0.y + a1.y + a2.y + a3.y,
                                   a0.z + a1.z + a2.z + a3.z,
                                   a0.w + a1.w + a2.w + a3.w);
            rn4[t] = make_float4(rsqrtf(fmaxf(s.x, 1e-20f)),
                                 rsqrtf(fmaxf(s.y, 1e-20f)),
                                 rsqrtf(fmaxf(s.z, 1e-20f)),
                                 rsqrtf(fmaxf(s.w, 1e-20f)));
        }
        __syncthreads();
        float4 rr = rn4[g];
        ushort* dst = Z + (size_t)(b * ZR + side * C_) * N_ + n0 + 4 * g;
#pragma unroll
        for (int i = 0; i < 8; ++i) {
            ushort4 pk;
            pk.x = rne16(raw[i].x * rr.x);
            pk.y = rne16(raw[i].y * rr.y);
            pk.z = rne16(raw[i].z * rr.z);
            pk.w = rne16(raw[i].w * rr.w);
            *(ushort4*)(dst + (size_t)(rc * 8 + i) * N_) = pk;   // 8B store
        }
        __syncthreads();   // rp reuse next side
    }
}

// ---------------- kernel 2 (cooperative): gram -> reduce -> final ---------
// grid: exactly 256 blocks x 256 threads (1 block/CU co-resident).
// Phase A: 256 gram tasks (b, s, q): q=0 GA=A A^T, q=1 GB=B B^T,
//          q=2 P=B A^T, q=3 PT=A B^T (so phase B has zero transposed reads).
// Phase B: 256 (b,seg) coalesced reduce tasks -> prt[blk].
// Phase C: block 0 sums 256 partials -> out.
__global__ __launch_bounds__(256) void coop_k(const ushort* __restrict__ Z,
                                              float* __restrict__ Wp,
                                              double* __restrict__ prt,
                                              float* __restrict__ out) {
    __shared__ float4 lds[4096];            // 64 KB: 2 dbuf x (A 1024 | B 1024)
    int blk = blockIdx.x;
    int t   = threadIdx.x;

    // ================= phase A: gram =================
    {
        int q = blk & 3;
        int s = (blk >> 2) & 3;
        int b = blk >> 4;
        int side_i = (q == 1 || q == 2);    // operand rows (output rows i)
        int side_j = (q == 1 || q == 3);    // operand rows (output cols j)
        bool same = (side_i == side_j);

        int lane = t & 63;
        int w    = t >> 6;
        int wr = (w >> 1) * 64;
        int wc = (w & 1) * 64;

        const ushort* Zb   = Z + (size_t)b * ZR * N_;
        const ushort* srcA = Zb + (size_t)(side_i * C_) * N_;
        const ushort* srcB = Zb + (size_t)(side_j * C_) * N_;
        int Boff = same ? 0 : 1024;

        f32x4 acc[4][4];
#pragma unroll
        for (int m = 0; m < 4; ++m)
#pragma unroll
            for (int n = 0; n < 4; ++n) acc[m][n] = (f32x4){0.f, 0.f, 0.f, 0.f};

        auto stage = [&](int dbuf, int ch) {
            int kc0 = s * KPB + ch * KC;
            float4* base = lds + dbuf * 2048;
#pragma unroll
            for (int it = 0; it < 4; ++it) {
                int r  = it * 32 + (t >> 3);
                int gl = (t & 7) ^ (r & 7);          // involution swizzle
                const ushort* gp = srcA + (size_t)r * N_ + kc0 + gl * 8;
                __builtin_amdgcn_global_load_lds(
                    (const __attribute__((address_space(1))) void*)gp,
                    (__attribute__((address_space(3))) void*)(base + it * 256 + t),
                    16, 0, 0);
            }
            if (!same) {
#pragma unroll
                for (int it = 0; it < 4; ++it) {
                    int r  = it * 32 + (t >> 3);
                    int gl = (t & 7) ^ (r & 7);
                    const ushort* gp = srcB + (size_t)r * N_ + kc0 + gl * 8;
                    __builtin_amdgcn_global_load_lds(
                        (const __attribute__((address_space(1))) void*)gp,
                        (__attribute__((address_space(3))) void*)(base + 1024 + it * 256 + t),
                        16, 0, 0);
                }
            }
        };

        auto compute = [&](int dbuf) {
            const bf16x8* L = (const bf16x8*)(lds + dbuf * 2048);
#pragma unroll
            for (int kk = 0; kk < 2; ++kk) {
                bf16x8 aA[4], aB[4];
                int gl = kk * 4 + (lane >> 4);
#pragma unroll
                for (int m = 0; m < 4; ++m) {
                    int r = wr + m * 16 + (lane & 15);
                    aA[m] = L[r * 8 + (gl ^ (r & 7))];
                }
#pragma unroll
                for (int n = 0; n < 4; ++n) {
                    int r = wc + n * 16 + (lane & 15);
                    aB[n] = L[Boff + r * 8 + (gl ^ (r & 7))];
                }
#pragma unroll
                for (int m = 0; m < 4; ++m)
#pragma unroll
                    for (int n = 0; n < 4; ++n)
                        acc[m][n] = __builtin_amdgcn_mfma_f32_16x16x32_bf16(
                            aA[m], aB[n], acc[m][n], 0, 0, 0);
            }
        };

        stage(0, 0);
        int buf = 0;
        for (int ch = 0; ch < NCH; ++ch) {
            __syncthreads();
            if (ch + 1 < NCH) stage(buf ^ 1, ch + 1);
            compute(buf);
            buf ^= 1;
        }

        float* Wq = Wp + ((size_t)((s * B_ + b) * 4 + q) << 14);
#pragma unroll
        for (int m = 0; m < 4; ++m) {
            int row0 = wr + m * 16 + (lane >> 4) * 4;
#pragma unroll
            for (int n = 0; n < 4; ++n) {
                int col = wc + n * 16 + (lane & 15);
#pragma unroll
                for (int v = 0; v < 4; ++v)
                    Wq[(size_t)(row0 + v) * C_ + col] = acc[m][n][v];
            }
        }
    }

    cg::this_grid().sync();

    // ================= phase B: coalesced reduce =================
    {
        int b   = blk >> 4;
        int seg = blk & 15;
        double s1 = 0.0, s2 = 0.0;
#pragma unroll
        for (int ii = 0; ii < 4; ++ii) {
            int idx = seg * 1024 + ii * 256 + t;     // 0..16383
            float ga = 0.f, gb = 0.f, p = 0.f, pt = 0.f;
#pragma unroll
            for (int s = 0; s < KS; ++s) {
                const float* Wb = Wp + ((size_t)((s * B_ + b) * 4) << 14);
                ga += Wb[idx];
                gb += Wb[QT + idx];
                p  += Wb[2 * QT + idx];
                pt += Wb[3 * QT + idx];
            }
            s1 += (double)ga * (double)gb;
            s2 += (double)p * (double)pt;
        }
        double v = s1 - s2;
#pragma unroll
        for (int o = 32; o > 0; o >>= 1) v += __shfl_down(v, o, 64);
        double* sd = (double*)lds;
        if ((t & 63) == 0) sd[t >> 6] = v;
        __syncthreads();
        if (t == 0) prt[blk] = sd[0] + sd[1] + sd[2] + sd[3];
    }

    cg::this_grid().sync();

    // ================= phase C: final scalar (block 0) =================
    if (blk == 0) {
        double v = prt[t];                  // 256 partials
#pragma unroll
        for (int o = 32; o > 0; o >>= 1) v += __shfl_down(v, o, 64);
        double* sd = (double*)lds;
        __syncthreads();
        if ((t & 63) == 0) sd[t >> 6] = v;
        __syncthreads();
        if (t == 0)
            out[0] = (float)(2.0 * (sd[0] + sd[1] + sd[2] + sd[3])
                             / ((double)B_ * (double)N_ * (double)N_));
    }
}

extern "C" void kernel_launch(void* const* d_in, const int* in_sizes, int n_in,
                              void* d_out, int out_size, void* d_ws, size_t ws_size,
                              hipStream_t stream) {
    const float* pred = (const float*)d_in[0];
    const float* targ = (const float*)d_in[1];
    float* out = (float*)d_out;

    // workspace layout (bytes):
    //   Z  : B_*ZR*N_*2       = 18,874,368  (bf16, normalized)
    //   Wp : KS*B_*4*QT*4     = 16,777,216  (fp32 partial quadrants)
    //   prt: 256 doubles      =      2,048
    char* ws = (char*)d_ws;
    ushort* Z   = (ushort*)ws;
    float*  Wp  = (float*)(ws + (size_t)B_ * ZR * N_ * 2);
    double* prt = (double*)(ws + (size_t)B_ * ZR * N_ * 2
                               + (size_t)KS * B_ * 4 * QT * 4);

    nc_k<<<B_ * 36, 256, 0, stream>>>(pred, targ, Z);

    void* args[] = {(void*)&Z, (void*)&Wp, (void*)&prt, (void*)&out};
    hipLaunchCooperativeKernel((void*)coop_k, dim3(256), dim3(256),
                               args, 0, stream);
}

// Round 6
// 33.565 us; speedup vs baseline: 3.2420x; 3.2420x over previous
//
#include <hip/hip_runtime.h>

#define B_   16
#define C_   128
#define N_   2304      // 48*48
#define ZR   256       // 2*C
#define KS   4         // k-splits for gram
#define KPB  (N_/KS)   // 576
#define KC   64        // k per staged chunk (64 bf16 = 8 granules of 16B)
#define NCH  (KPB/KC)  // 9
#define QT   16384     // 128*128 floats per quadrant tile

typedef __bf16 bf16x8 __attribute__((ext_vector_type(8)));
typedef float  f32x4  __attribute__((ext_vector_type(4)));

__device__ __forceinline__ ushort rne16(float f) {
    unsigned u = __float_as_uint(f);
    return (ushort)((u + 0x7FFFu + ((u >> 16) & 1u)) >> 16);   // RNE bf16
}

// ---------------- kernel 1: norms + normalize + bf16 convert (float4) ----
// grid: B_*2*36 = 1152 blocks, 256 threads. Block = one side (pred/targ),
// one batch, 64 columns. Thread (g=t&15, rc=t>>4): cols 4g..4g+3, rows
// rc*8..rc*8+7. Raw data stays in registers across the norm reduction.
__global__ __launch_bounds__(256) void nc_k(const float* __restrict__ pred,
                                            const float* __restrict__ targ,
                                            ushort* __restrict__ Z) {
    int blk  = blockIdx.x;
    int b    = blk / 72;
    int rem  = blk % 72;
    int side = rem / 36;
    int n0   = (rem % 36) * 64;
    int t  = threadIdx.x;
    int g  = t & 15;
    int rc = t >> 4;

    __shared__ float4 rp[16][16];
    __shared__ float4 rq[4][16];
    __shared__ float4 rn4[16];

    const float* src = (side ? targ : pred) + (size_t)b * C_ * N_ + n0 + 4 * g;
    float4 raw[8];
    float4 sq = make_float4(0.f, 0.f, 0.f, 0.f);
#pragma unroll
    for (int i = 0; i < 8; ++i) {
        raw[i] = *(const float4*)(src + (size_t)(rc * 8 + i) * N_);
        sq.x = fmaf(raw[i].x, raw[i].x, sq.x);
        sq.y = fmaf(raw[i].y, raw[i].y, sq.y);
        sq.z = fmaf(raw[i].z, raw[i].z, sq.z);
        sq.w = fmaf(raw[i].w, raw[i].w, sq.w);
    }
    rp[rc][g] = sq;
    __syncthreads();
    if (t < 64) {
        int gg = t & 15, h = t >> 4;
        float4 a0 = rp[h * 4 + 0][gg], a1 = rp[h * 4 + 1][gg];
        float4 a2 = rp[h * 4 + 2][gg], a3 = rp[h * 4 + 3][gg];
        rq[h][gg] = make_float4(a0.x + a1.x + a2.x + a3.x,
                                a0.y + a1.y + a2.y + a3.y,
                                a0.z + a1.z + a2.z + a3.z,
                                a0.w + a1.w + a2.w + a3.w);
    }
    __syncthreads();
    if (t < 16) {
        float4 a0 = rq[0][t], a1 = rq[1][t], a2 = rq[2][t], a3 = rq[3][t];
        float4 s = make_float4(a0.x + a1.x + a2.x + a3.x,
                               a0.y + a1.y + a2.y + a3.y,
                               a0.z + a1.z + a2.z + a3.z,
                               a0.w + a1.w + a2.w + a3.w);
        rn4[t] = make_float4(rsqrtf(fmaxf(s.x, 1e-20f)),
                             rsqrtf(fmaxf(s.y, 1e-20f)),
                             rsqrtf(fmaxf(s.z, 1e-20f)),
                             rsqrtf(fmaxf(s.w, 1e-20f)));
    }
    __syncthreads();
    float4 rr = rn4[g];
    ushort* dst = Z + (size_t)(b * ZR + side * C_) * N_ + n0 + 4 * g;
#pragma unroll
    for (int i = 0; i < 8; ++i) {
        ushort4 pk;
        pk.x = rne16(raw[i].x * rr.x);
        pk.y = rne16(raw[i].y * rr.y);
        pk.z = rne16(raw[i].z * rr.z);
        pk.w = rne16(raw[i].w * rr.w);
        *(ushort4*)(dst + (size_t)(rc * 8 + i) * N_) = pk;   // 8B store
    }
}

// ---------------- kernel 2: partial Gram quadrants via bf16 MFMA ----------
// grid: B_*KS*4 = 256 blocks (1/CU), 256 threads (4 waves). Block =
// (batch, ksplit, quadrant q): q=0 GA=A A^T, q=1 GB=B B^T, q=2 P=B A^T,
// q=3 PT=A B^T (so the reduce has zero transposed reads). Each wave: one
// 64x64 of the 128x128 quadrant. Staging: global_load_lds width16, linear
// LDS dest + involution-swizzled global source; frag reads apply the same
// swizzle (conflict-free). Plain stores, no init needed.
__global__ __launch_bounds__(256) void gram_k(const ushort* __restrict__ Z,
                                              float* __restrict__ Wp) {
    int blk = blockIdx.x;
    int q = blk & 3;
    int s = (blk >> 2) & 3;
    int b = blk >> 4;
    int side_i = (q == 1 || q == 2);    // operand rows -> output rows i
    int side_j = (q == 1 || q == 3);    // operand rows -> output cols j
    bool same = (side_i == side_j);

    int t    = threadIdx.x;
    int lane = t & 63;
    int w    = t >> 6;
    int wr = (w >> 1) * 64;
    int wc = (w & 1) * 64;

    __shared__ float4 lds[4096];            // 64 KB: 2 dbuf x (A 1024 | B 1024)

    const ushort* Zb   = Z + (size_t)b * ZR * N_;
    const ushort* srcA = Zb + (size_t)(side_i * C_) * N_;
    const ushort* srcB = Zb + (size_t)(side_j * C_) * N_;
    int Boff = same ? 0 : 1024;

    f32x4 acc[4][4];
#pragma unroll
    for (int m = 0; m < 4; ++m)
#pragma unroll
        for (int n = 0; n < 4; ++n) acc[m][n] = (f32x4){0.f, 0.f, 0.f, 0.f};

    auto stage = [&](int dbuf, int ch) {
        int kc0 = s * KPB + ch * KC;
        float4* base = lds + dbuf * 2048;
#pragma unroll
        for (int it = 0; it < 4; ++it) {
            int r  = it * 32 + (t >> 3);
            int gl = (t & 7) ^ (r & 7);          // involution swizzle
            const ushort* gp = srcA + (size_t)r * N_ + kc0 + gl * 8;
            __builtin_amdgcn_global_load_lds(
                (const __attribute__((address_space(1))) void*)gp,
                (__attribute__((address_space(3))) void*)(base + it * 256 + t),
                16, 0, 0);
        }
        if (!same) {
#pragma unroll
            for (int it = 0; it < 4; ++it) {
                int r  = it * 32 + (t >> 3);
                int gl = (t & 7) ^ (r & 7);
                const ushort* gp = srcB + (size_t)r * N_ + kc0 + gl * 8;
                __builtin_amdgcn_global_load_lds(
                    (const __attribute__((address_space(1))) void*)gp,
                    (__attribute__((address_space(3))) void*)(base + 1024 + it * 256 + t),
                    16, 0, 0);
            }
        }
    };

    auto compute = [&](int dbuf) {
        const bf16x8* L = (const bf16x8*)(lds + dbuf * 2048);
#pragma unroll
        for (int kk = 0; kk < 2; ++kk) {
            bf16x8 aA[4], aB[4];
            int gl = kk * 4 + (lane >> 4);
#pragma unroll
            for (int m = 0; m < 4; ++m) {
                int r = wr + m * 16 + (lane & 15);
                aA[m] = L[r * 8 + (gl ^ (r & 7))];
            }
#pragma unroll
            for (int n = 0; n < 4; ++n) {
                int r = wc + n * 16 + (lane & 15);
                aB[n] = L[Boff + r * 8 + (gl ^ (r & 7))];
            }
#pragma unroll
            for (int m = 0; m < 4; ++m)
#pragma unroll
                for (int n = 0; n < 4; ++n)
                    acc[m][n] = __builtin_amdgcn_mfma_f32_16x16x32_bf16(
                        aA[m], aB[n], acc[m][n], 0, 0, 0);
        }
    };

    stage(0, 0);
    int buf = 0;
    for (int ch = 0; ch < NCH; ++ch) {
        __syncthreads();                    // drains vmcnt: chunk ch landed
        if (ch + 1 < NCH) stage(buf ^ 1, ch + 1);
        compute(buf);
        buf ^= 1;
    }

    float* Wq = Wp + ((size_t)((s * B_ + b) * 4 + q) << 14);
#pragma unroll
    for (int m = 0; m < 4; ++m) {
        int row0 = wr + m * 16 + (lane >> 4) * 4;
#pragma unroll
        for (int n = 0; n < 4; ++n) {
            int col = wc + n * 16 + (lane & 15);
#pragma unroll
            for (int v = 0; v < 4; ++v)
                Wq[(size_t)(row0 + v) * C_ + col] = acc[m][n][v];
        }
    }
}

// ---------------- kernel 3: per-(batch,seg) S1 - S2 in double ----------------
// grid: 256 blocks (16 per batch), fully coalesced reads of all 4 streams.
__global__ __launch_bounds__(256) void reduce_k(const float* __restrict__ Wp,
                                                double* __restrict__ prt) {
    int blk = blockIdx.x;
    int b   = blk >> 4;
    int seg = blk & 15;
    int t   = threadIdx.x;
    double s1 = 0.0, s2 = 0.0;
#pragma unroll
    for (int ii = 0; ii < 4; ++ii) {
        int idx = seg * 1024 + ii * 256 + t;     // 0..16383 over (i,j)
        float ga = 0.f, gb = 0.f, p = 0.f, pt = 0.f;
#pragma unroll
        for (int s = 0; s < KS; ++s) {
            const float* Wb = Wp + ((size_t)((s * B_ + b) * 4) << 14);
            ga += Wb[idx];                // GA[i,j]
            gb += Wb[QT + idx];           // GB[i,j]
            p  += Wb[2 * QT + idx];       // P[i,j]
            pt += Wb[3 * QT + idx];       // P^T[i,j] = P[j,i]
        }
        s1 += (double)ga * (double)gb;
        s2 += (double)p * (double)pt;
    }
    double v = s1 - s2;
    __shared__ double sd[4];
#pragma unroll
    for (int o = 32; o > 0; o >>= 1) v += __shfl_down(v, o, 64);
    if ((t & 63) == 0) sd[t >> 6] = v;
    __syncthreads();
    if (t == 0) prt[blk] = sd[0] + sd[1] + sd[2] + sd[3];
}

// ---------------- kernel 4: final scalar ----------------
__global__ __launch_bounds__(256) void final_k(const double* __restrict__ prt,
                                               float* __restrict__ out) {
    int t = threadIdx.x;
    double v = prt[t];                  // 256 partials
#pragma unroll
    for (int o = 32; o > 0; o >>= 1) v += __shfl_down(v, o, 64);
    __shared__ double sd[4];
    if ((t & 63) == 0) sd[t >> 6] = v;
    __syncthreads();
    if (t == 0)
        out[0] = (float)(2.0 * (sd[0] + sd[1] + sd[2] + sd[3])
                         / ((double)B_ * (double)N_ * (double)N_));
}

extern "C" void kernel_launch(void* const* d_in, const int* in_sizes, int n_in,
                              void* d_out, int out_size, void* d_ws, size_t ws_size,
                              hipStream_t stream) {
    const float* pred = (const float*)d_in[0];
    const float* targ = (const float*)d_in[1];
    float* out = (float*)d_out;

    // workspace layout (bytes):
    //   Z  : B_*ZR*N_*2       = 18,874,368  (bf16, normalized)
    //   Wp : KS*B_*4*QT*4     = 16,777,216  (fp32 partial quadrants)
    //   prt: 256 doubles      =      2,048
    char* ws = (char*)d_ws;
    ushort* Z   = (ushort*)ws;
    float*  Wp  = (float*)(ws + (size_t)B_ * ZR * N_ * 2);
    double* prt = (double*)(ws + (size_t)B_ * ZR * N_ * 2
                               + (size_t)KS * B_ * 4 * QT * 4);

    nc_k<<<B_ * 2 * 36, 256, 0, stream>>>(pred, targ, Z);
    gram_k<<<B_ * KS * 4, 256, 0, stream>>>(Z, Wp);
    reduce_k<<<256, 256, 0, stream>>>(Wp, prt);
    final_k<<<1, 256, 0, stream>>>(prt, out);
}